// Round 4
// baseline (148.067 us; speedup 1.0000x reference)
//
#include <hip/hip_runtime.h>

// out[i_local, j] = dis2  if (j > i) & neighbor-voxel & (dis2 < sum_radii_sq) & (ri < 1)
//                 = 0     otherwise,  i = start_idx + i_local.
//
// Voxel-equivalence: valid requires dis2 < srs <= 0.49, which forces
// |ci - cj| <= 1 per axis (voxel 1.0), under which 27-neighbor hash
// membership is exactly true; hash collisions only add pairs that fail the
// distance test. Bit-exact vs numpy via _rn ops with ((dx2+dy2)+dz2).
//
// R1: 8 rows/block — j-side loads amortized.
// R2: wave-uniform neighbor-skip + nontemporal stores.
// R3: fix — nontemporal builtin needs a NATIVE vector type (ext_vector_type),
//     not HIP's float4 class.

#define ROWS 8

typedef float v4f __attribute__((ext_vector_type(4)));

__global__ __launch_bounds__(256) void pair_dist_kernel(
    const float* __restrict__ pts,   // (n,3) fp32
    const float* __restrict__ rad,   // (n,)  fp32
    const int*  __restrict__ start_ptr,
    float* __restrict__ out,         // (chunk, n) fp32
    int n)
{
    const int start = *start_ptr;                      // wave-uniform
    const int row0  = blockIdx.y * ROWS;               // i_local base
    const int tcol  = blockIdx.x * 256 + threadIdx.x;  // float4 column index
    const int j0    = tcol * 4;

    // ---- j-side data: loaded once, reused for all ROWS rows ----
    const float4* p4 = (const float4*)(pts + (size_t)j0 * 3);
    const float4 a = p4[0];
    const float4 b = p4[1];
    const float4 c = p4[2];
    const float pjx[4] = {a.x, a.w, b.z, c.y};
    const float pjy[4] = {a.y, b.x, b.w, c.z};
    const float pjz[4] = {a.z, b.y, c.x, c.w};

    const float4 r4 = *(const float4*)(rad + j0);
    const float rj[4] = {r4.x, r4.y, r4.z, r4.w};

    int cjx[4], cjy[4], cjz[4];
    #pragma unroll
    for (int k = 0; k < 4; ++k) {
        cjx[k] = (int)pjx[k];
        cjy[k] = (int)pjy[k];
        cjz[k] = (int)pjz[k];
    }

    // ---- i-side row scalars: uniform per block -> scalar loads ----
    float xi[ROWS], yi[ROWS], zi[ROWS], ri[ROWS];
    #pragma unroll
    for (int r = 0; r < ROWS; ++r) {
        const int i = start + row0 + r;
        xi[r] = pts[i * 3 + 0];
        yi[r] = pts[i * 3 + 1];
        zi[r] = pts[i * 3 + 2];
        ri[r] = rad[i];
    }

    const size_t row_pitch = (size_t)(n >> 2);
    #pragma unroll
    for (int r = 0; r < ROWS; ++r) {
        const int   il  = row0 + r;
        const int   i   = start + il;
        const float x   = xi[r], y = yi[r], z = zi[r], rri = ri[r];
        const int   cix = (int)x, ciy = (int)y, ciz = (int)z;
        const bool  ri_ok = rri < 1.0f;                // DIS_THRESHOLD

        // Cheap int voxel-neighbor test for the 4 columns.
        bool nb[4];
        int  anynb = 0;
        #pragma unroll
        for (int k = 0; k < 4; ++k) {
            // |ci - cj| <= 1 via unsigned trick: (u32)(d + 1) <= 2
            nb[k] = ((unsigned)(cix - cjx[k] + 1) <= 2u) &&
                    ((unsigned)(ciy - cjy[k] + 1) <= 2u) &&
                    ((unsigned)(ciz - cjz[k] + 1) <= 2u);
            anynb |= (int)nb[k];
        }

        v4f res = (v4f){0.0f, 0.0f, 0.0f, 0.0f};

        // Wave-uniform skip: ~80% of (row, 256-col segment)s have no
        // voxel neighbor at this density -> store zeros, no fp math.
        if (ri_ok && __any(anynb)) {
            float o[4];
            #pragma unroll
            for (int k = 0; k < 4; ++k) {
                const int j = j0 + k;

                const float dx = __fsub_rn(x, pjx[k]);
                const float dy = __fsub_rn(y, pjy[k]);
                const float dz = __fsub_rn(z, pjz[k]);
                const float d2 = __fadd_rn(__fadd_rn(__fmul_rn(dx, dx),
                                                     __fmul_rn(dy, dy)),
                                           __fmul_rn(dz, dz));

                const float rjk   = rj[k];
                const float minr  = fminf(rri, rjk);
                const float max_r = __fmul_rn(minr, 1.5f);
                const float s     = __fadd_rn(fminf(rri, max_r),
                                              fminf(rjk, max_r));
                const float srs   = __fmul_rn(s, s);   // EDGE_DIST_SCALE == 1

                const bool valid = (j > i) && nb[k] && (d2 < srs);
                o[k] = valid ? d2 : 0.0f;
            }
            res = (v4f){o[0], o[1], o[2], o[3]};
        }

        // Streaming 134 MB output: nontemporal, coalesced 16B.
        v4f* dst = ((v4f*)out) + (size_t)il * row_pitch + tcol;
        __builtin_nontemporal_store(res, dst);
    }
}

extern "C" void kernel_launch(void* const* d_in, const int* in_sizes, int n_in,
                              void* d_out, int out_size, void* d_ws, size_t ws_size,
                              hipStream_t stream)
{
    const float* pts = (const float*)d_in[0];   // (n,3)
    const float* rad = (const float*)d_in[1];   // (n,1)
    const int* start_ptr = (const int*)d_in[2]; // scalar on device
    // d_in[3] = end_idx (unused; chunk derived from out_size)

    const int n     = in_sizes[0] / 3;          // 16384
    const int chunk = out_size / n;             // 2048

    dim3 grid(n / (256 * 4), chunk / ROWS);     // (16, 256)
    dim3 block(256);
    pair_dist_kernel<<<grid, block, 0, stream>>>(
        pts, rad, start_ptr, (float*)d_out, n);
}

// Round 5
// 142.500 us; speedup vs baseline: 1.0391x; 1.0391x over previous
//
#include <hip/hip_runtime.h>

// out[i_local, j] = dis2  if (j > i) & neighbor-voxel & (dis2 < sum_radii_sq) & (ri < 1)
//                 = 0     otherwise,  i = start_idx + i_local.
//
// Voxel-equivalence: valid requires dis2 < srs <= 0.49, which forces
// |ci - cj| <= 1 per axis (voxel 1.0), under which 27-neighbor hash
// membership is exactly true; hash collisions only add pairs that fail the
// distance test. Bit-exact vs numpy via _rn ops with ((dx2+dy2)+dz2).
//
// R1: 8 rows/block — j-side loads amortized.
// R2/R3: wave-uniform neighbor-skip (neutral), nontemporal store (neutral).
// R4: long-lived waves — each block grid-strides over 4 row-groups
//     (32 stores/thread, rolled loop), amortizing the ~1000-cycle wave
//     startup chain (kernarg -> start load -> j-loads) that was capping
//     in-flight store bytes at ~2 KB/CU (~3.6 TB/s observed vs 6.4 fill).
//     Normal stores (match the 6.4 TB/s fill path).

#define ROWS   8
#define YITER  4

typedef float v4f __attribute__((ext_vector_type(4)));

__global__ __launch_bounds__(256) void pair_dist_kernel(
    const float* __restrict__ pts,   // (n,3) fp32
    const float* __restrict__ rad,   // (n,)  fp32
    const int*  __restrict__ start_ptr,
    float* __restrict__ out,         // (chunk, n) fp32
    int n)
{
    const int start = *start_ptr;                      // wave-uniform
    const int tcol  = blockIdx.x * 256 + threadIdx.x;  // float4 column index
    const int j0    = tcol * 4;
    const int ngroups = gridDim.y;                     // row-groups per pass

    // ---- j-side data: loaded once, reused for all YITER*ROWS rows ----
    const float4* p4 = (const float4*)(pts + (size_t)j0 * 3);
    const float4 a = p4[0];
    const float4 b = p4[1];
    const float4 c = p4[2];
    const float pjx[4] = {a.x, a.w, b.z, c.y};
    const float pjy[4] = {a.y, b.x, b.w, c.z};
    const float pjz[4] = {a.z, b.y, c.x, c.w};

    const float4 r4 = *(const float4*)(rad + j0);
    const float rj[4] = {r4.x, r4.y, r4.z, r4.w};

    int cjx[4], cjy[4], cjz[4];
    #pragma unroll
    for (int k = 0; k < 4; ++k) {
        cjx[k] = (int)pjx[k];
        cjy[k] = (int)pjy[k];
        cjz[k] = (int)pjz[k];
    }

    const size_t row_pitch = (size_t)(n >> 2);

    // Rolled outer loop: keeps waves long-lived (store queue stays full)
    // and VGPR use flat (i-side reloaded per group).
    #pragma unroll 1
    for (int t = 0; t < YITER; ++t) {
        const int grp  = blockIdx.y + t * ngroups;     // row-group index
        const int row0 = grp * ROWS;

        // i-side row scalars: uniform per block -> scalar loads.
        float xi[ROWS], yi[ROWS], zi[ROWS], ri[ROWS];
        #pragma unroll
        for (int r = 0; r < ROWS; ++r) {
            const int i = start + row0 + r;
            xi[r] = pts[i * 3 + 0];
            yi[r] = pts[i * 3 + 1];
            zi[r] = pts[i * 3 + 2];
            ri[r] = rad[i];
        }

        #pragma unroll
        for (int r = 0; r < ROWS; ++r) {
            const int   il  = row0 + r;
            const int   i   = start + il;
            const float x   = xi[r], y = yi[r], z = zi[r], rri = ri[r];
            const int   cix = (int)x, ciy = (int)y, ciz = (int)z;
            const bool  ri_ok = rri < 1.0f;            // DIS_THRESHOLD

            // Cheap int voxel-neighbor test for the 4 columns.
            bool nb[4];
            int  anynb = 0;
            #pragma unroll
            for (int k = 0; k < 4; ++k) {
                // |ci - cj| <= 1 via unsigned trick: (u32)(d + 1) <= 2
                nb[k] = ((unsigned)(cix - cjx[k] + 1) <= 2u) &&
                        ((unsigned)(ciy - cjy[k] + 1) <= 2u) &&
                        ((unsigned)(ciz - cjz[k] + 1) <= 2u);
                anynb |= (int)nb[k];
            }

            v4f res = (v4f){0.0f, 0.0f, 0.0f, 0.0f};

            // Wave-uniform skip: most (row, 256-col segment)s have no
            // voxel neighbor at this density -> store zeros, no fp math.
            if (ri_ok && __any(anynb)) {
                float o[4];
                #pragma unroll
                for (int k = 0; k < 4; ++k) {
                    const int j = j0 + k;

                    const float dx = __fsub_rn(x, pjx[k]);
                    const float dy = __fsub_rn(y, pjy[k]);
                    const float dz = __fsub_rn(z, pjz[k]);
                    const float d2 = __fadd_rn(__fadd_rn(__fmul_rn(dx, dx),
                                                         __fmul_rn(dy, dy)),
                                               __fmul_rn(dz, dz));

                    const float rjk   = rj[k];
                    const float minr  = fminf(rri, rjk);
                    const float max_r = __fmul_rn(minr, 1.5f);
                    const float s     = __fadd_rn(fminf(rri, max_r),
                                                  fminf(rjk, max_r));
                    const float srs   = __fmul_rn(s, s); // EDGE_DIST_SCALE==1

                    const bool valid = (j > i) && nb[k] && (d2 < srs);
                    o[k] = valid ? d2 : 0.0f;
                }
                res = (v4f){o[0], o[1], o[2], o[3]};
            }

            // Coalesced 16B store (wave writes 1 KB contiguous per row).
            ((v4f*)out)[(size_t)il * row_pitch + tcol] = res;
        }
    }
}

extern "C" void kernel_launch(void* const* d_in, const int* in_sizes, int n_in,
                              void* d_out, int out_size, void* d_ws, size_t ws_size,
                              hipStream_t stream)
{
    const float* pts = (const float*)d_in[0];   // (n,3)
    const float* rad = (const float*)d_in[1];   // (n,1)
    const int* start_ptr = (const int*)d_in[2]; // scalar on device
    // d_in[3] = end_idx (unused; chunk derived from out_size)

    const int n     = in_sizes[0] / 3;          // 16384
    const int chunk = out_size / n;             // 2048

    dim3 grid(n / (256 * 4), chunk / (ROWS * YITER));  // (16, 64) = 1024 blocks
    dim3 block(256);
    pair_dist_kernel<<<grid, block, 0, stream>>>(
        pts, rad, start_ptr, (float*)d_out, n);
}